// Round 3
// baseline (3029.232 us; speedup 1.0000x reference)
//
#include <hip/hip_runtime.h>

// ---------------- constants ----------------
#define NTOK 4096         // B*P patches
#define CH   2048         // patches per stage-2 chunk
#define NCHUNK 2

typedef _Float16 f16;
typedef __attribute__((ext_vector_type(8))) _Float16 half8;
typedef __attribute__((ext_vector_type(4))) _Float16 half4;
typedef __attribute__((ext_vector_type(4))) float f32x4;

// converted-weight layout (f16 elements) inside workspace
#define OFF_INPW 0
#define OFF_WQKV (512*128)
#define OFF_WO   (OFF_WQKV + 3*512*512)
#define OFF_W1   (OFF_WO + 512*512)
#define OFF_W2   (OFF_W1 + 512*512)
#define OFF_GW   (OFF_W2 + 512*512)       // 2 layers x [gwq|gwk|gwv|gwo]
#define WBF_TOT  (OFF_GW + 8*512*512)

static __device__ __forceinline__ f32x4 mfma16(half8 a, half8 b, f32x4 c){
  return __builtin_amdgcn_mfma_f32_16x16x32_f16(a, b, c, 0, 0, 0);
}

static __device__ __forceinline__ void gld_lds16(const f16* g, f16* l){
  __builtin_amdgcn_global_load_lds(
      (const __attribute__((address_space(1))) void*)g,
      (__attribute__((address_space(3))) void*)l, 16, 0, 0);
}

// ---------------- weight conversion ----------------
__global__ __launch_bounds__(256) void conv_weights(
    const float* __restrict__ inpw, const float* __restrict__ wq, const float* __restrict__ wk,
    const float* __restrict__ wv, const float* __restrict__ wo, const float* __restrict__ w1,
    const float* __restrict__ w2, const float* __restrict__ gwq, const float* __restrict__ gwk,
    const float* __restrict__ gwv, const float* __restrict__ gwo, f16* __restrict__ wbf,
    const float* __restrict__ bq, const float* __restrict__ bk, const float* __restrict__ bv,
    const float* __restrict__ gbq, const float* __restrict__ gbk, const float* __restrict__ gbv,
    float* __restrict__ biasb)
{
  int e = blockIdx.x*256 + threadIdx.x;
  int y = blockIdx.y;
  if (y == 0){
    if (e < 512*128){
      int row = e>>7, col = e&127;
      float v = (col < 80) ? inpw[row*80 + col] : 0.f;
      wbf[OFF_INPW + e] = (f16)v;
    }
    return;
  }
  if (y == 15){
    if (e < 1536){
      biasb[e] = (e < 512) ? bq[e] : (e < 1024 ? bk[e-512] : bv[e-1024]);
    } else if (e < 3*1536){
      int idx = e - 1536, li = idx/1536, c = idx - li*1536;
      float v = (c < 512) ? gbq[li*512 + c] : (c < 1024 ? gbk[li*512 + c-512] : gbv[li*512 + c-1024]);
      biasb[e] = v;
    }
    return;
  }
  if (e >= 512*512) return;
  const float* src; int off;
  if (y <= 6){
    const float* tab[6] = {wq, wk, wv, wo, w1, w2};
    src = tab[y-1]; off = OFF_WQKV + (y-1)*512*512;
  } else {
    int idx = y-7; int li = idx>>2, part = idx&3;
    const float* tab[4] = {gwq, gwk, gwv, gwo};
    src = tab[part] + (size_t)li*512*512; off = OFF_GW + idx*512*512;
  }
  wbf[off + e] = (f16)src[e];
}

// ---------------- per-patch mask aux ----------------
__global__ __launch_bounds__(256) void build_mask(
    const int* __restrict__ mask, float* __restrict__ mb, float* __restrict__ pex)
{
  int wv = threadIdx.x>>6, lane = threadIdx.x&63;
  int n = blockIdx.x*4 + wv;
  int valid = mask[(size_t)n*64 + lane] > 0;
  unsigned long long ball = __ballot(valid);
  int hasany = (ball != 0ull);
  int masked = (lane == 0) ? (!valid && hasany) : (!valid);
  mb[(size_t)n*64 + lane] = masked ? -1e9f : 0.f;
  if (lane == 0) pex[n] = hasany ? 1.f : 0.f;
}

// ---------------- pts: [x | te1 | sin(te2) | 0-pad] -> f16 [rows][128] ----------------
__global__ __launch_bounds__(256) void pts_build(
    const float* __restrict__ x, const float* __restrict__ tt,
    const float* __restrict__ tsw, const float* __restrict__ tsb,
    const float* __restrict__ tpw, const float* __restrict__ tpb,
    f16* __restrict__ pts, int rowbase)
{
  int e = blockIdx.x*256 + threadIdx.x;        // CH*64*128 exact
  int r = e>>7, col = e&127;
  size_t grow = (size_t)rowbase + r;
  float v;
  if (col < 16) v = x[grow*16 + col];
  else if (col >= 80) v = 0.f;
  else {
    float t = tt[grow];
    if (col == 16) v = t*tsw[0] + tsb[0];
    else           v = __sinf(t*tpw[col-17] + tpb[col-17]);
  }
  pts[e] = (f16)v;
}

// ---------------- MFMA GEMM: C[M,*] = A[M,K](lda) @ W[N,K]^T, 128x128 tile ----------
// (used for K=128 h0 gemm and small-M stage-3 gemms)
template<int RESID, bool RELU, bool OUTF32, bool ZEMPTY>
__global__ __launch_bounds__(256) void gemm128(
    const f16* __restrict__ A, const f16* __restrict__ W, const float* __restrict__ bias,
    void* __restrict__ Cout, const void* __restrict__ Rsd, const float* __restrict__ pex,
    int K, int lda, int ldc, int nbase)
{
  __shared__ __align__(16) f16 As[128][64];
  __shared__ __align__(16) f16 Bs[128][64];
  const int tid = threadIdx.x;
  const int m0 = blockIdx.x*128, n0 = blockIdx.y*128;
  const int wv = tid>>6, lane = tid&63, l15 = lane&15, quad = lane>>4;
  const int wm = (wv&1)*64, wn = (wv>>1)*64;
  const int srow = lane>>3;                 // row within 8-row group
  const int schunk = (lane&7) ^ srow;       // swizzled source chunk
  f32x4 acc[4][4] = {};
  for (int kc = 0; kc < K; kc += 64){
    __syncthreads();
    #pragma unroll
    for (int i=0; i<4; i++){
      const int rA = wv*32 + i*8;
      gld_lds16(A + (size_t)(m0 + rA + srow)*lda + kc + schunk*8, &As[rA][0]);
      gld_lds16(W + (size_t)(n0 + rA + srow)*K   + kc + schunk*8, &Bs[rA][0]);
    }
    __syncthreads();
    #pragma unroll
    for (int kk=0; kk<2; kk++){
      half8 av[4], bv8[4];
      #pragma unroll
      for (int t=0; t<4; t++){
        const int ra = wm + t*16 + l15;
        av[t]  = *(const half8*)(&As[ra][(((kk*4 + quad) ^ (ra&7)))*8]);
        const int rb = wn + t*16 + l15;
        bv8[t] = *(const half8*)(&Bs[rb][(((kk*4 + quad) ^ (rb&7)))*8]);
      }
      #pragma unroll
      for (int mt=0; mt<4; mt++)
        #pragma unroll
        for (int nt=0; nt<4; nt++)
          acc[mt][nt] = mfma16(av[mt], bv8[nt], acc[mt][nt]);
    }
  }
  #pragma unroll
  for (int mt=0; mt<4; mt++){
    #pragma unroll
    for (int nt=0; nt<4; nt++){
      #pragma unroll
      for (int i=0; i<4; i++){
        int gr = m0 + wm + mt*16 + quad*4 + i;
        int gc = n0 + wn + nt*16 + l15;
        float v = acc[mt][nt][i] + bias[gc];
        if (RELU) v = fmaxf(v, 0.f);
        if (RESID == 1) v += (float)((const f16*)Rsd)[(size_t)gr*ldc + gc];
        if (ZEMPTY){ if ((gr&63)==0 && pex[nbase + (gr>>6)]==0.f) v = 0.f; }
        if (RESID == 2) v = v*pex[gr] + ((const float*)Rsd)[(size_t)gr*ldc + gc];
        if (OUTF32) ((float*)Cout)[(size_t)gr*ldc + gc] = v;
        else        ((f16*)Cout)[(size_t)gr*ldc + gc] = (f16)v;
      }
    }
  }
}

// ---------------- fused per-patch tail: QKV -> attn -> WO -> LN1 -> FFN -> LN2 -> pool
// One block = one patch (64 tokens x 512). 4 waves; wave w handles heads 2w, 2w+1.
// HBM: read h0 tile (64 KB) + weights via L2; write 512 floats.
__global__ __launch_bounds__(256) void patch_block(
    const f16* __restrict__ h0g, const f16* __restrict__ wbf, const float* __restrict__ biasb,
    const float* __restrict__ bo, const float* __restrict__ b1f, const float* __restrict__ b2f,
    const float* __restrict__ g1, const float* __restrict__ be1,
    const float* __restrict__ g2, const float* __restrict__ be2,
    const float* __restrict__ eb, const float* __restrict__ mb,
    const int* __restrict__ mask, float* __restrict__ out, int nbase)
{
  __shared__ __align__(16) f16 Z[64*520];        // z plane, then h_ln plane
  __shared__ __align__(16) f16 SC[4*2*64*72];    // per-wave Q/Ps + K/Vt; later FFN f plane
  __shared__ float stS[64][4], stQ[64][4];
  __shared__ float mbs[64], vArr[64];

  const int tid = threadIdx.x, wv = tid>>6, lane = tid&63, l15 = lane&15, quad = lane>>4;
  const int n = blockIdx.x, ng = nbase + n;
  const size_t rbase = (size_t)n*64;

  if (tid < 64){
    mbs[tid]  = mb[(size_t)ng*64 + tid];
    vArr[tid] = (mask[(size_t)ng*64 + tid] > 0) ? 1.f : 0.f;
  }
  __syncthreads();

  f16* Qb = SC + wv*(2*64*72);   // [64][72]: Q, then Ps
  f16* Kb = Qb + 64*72;          // [64][72]: K, then V^T
  const f16* Wq = wbf + OFF_WQKV;

  // ================= Phase A: per-wave attention (2 heads) =================
  #pragma unroll 1
  for (int hr=0; hr<2; hr++){
    const int h = wv*2 + hr;
    // ---- Q,K = h0 @ wq_h^T / wk_h^T  (64x64, K=512) ----
    {
      f32x4 qa[4][4] = {}, ka[4][4] = {};
      #pragma unroll 4
      for (int ks=0; ks<16; ks++){
        half8 a[4], bq_[4], bk_[4];
        #pragma unroll
        for (int mt=0; mt<4; mt++)
          a[mt] = *(const half8*)(h0g + (rbase + mt*16 + l15)*512 + ks*32 + quad*8);
        #pragma unroll
        for (int nt=0; nt<4; nt++){
          bq_[nt] = *(const half8*)(Wq + (size_t)(h*64 + nt*16 + l15)*512 + ks*32 + quad*8);
          bk_[nt] = *(const half8*)(Wq + (size_t)(512 + h*64 + nt*16 + l15)*512 + ks*32 + quad*8);
        }
        #pragma unroll
        for (int mt=0; mt<4; mt++)
          #pragma unroll
          for (int nt=0; nt<4; nt++){
            qa[mt][nt] = mfma16(a[mt], bq_[nt], qa[mt][nt]);
            ka[mt][nt] = mfma16(a[mt], bk_[nt], ka[mt][nt]);
          }
      }
      #pragma unroll
      for (int nt=0; nt<4; nt++){
        float vbq = biasb[h*64 + nt*16 + l15];
        float vbk = biasb[512 + h*64 + nt*16 + l15];
        #pragma unroll
        for (int mt=0; mt<4; mt++)
          #pragma unroll
          for (int i=0; i<4; i++){
            int r = mt*16 + quad*4 + i, c = nt*16 + l15;
            Qb[r*72 + c] = (f16)(qa[mt][nt][i] + vbq);
            Kb[r*72 + c] = (f16)(ka[mt][nt][i] + vbk);
          }
      }
    }
    __syncthreads();
    // ---- scores + softmax; Ps overwrites Qb ----
    {
      f32x4 sacc[4][4] = {};
      #pragma unroll
      for (int kc=0; kc<2; kc++){
        half8 af[4], bf[4];
        #pragma unroll
        for (int t=0; t<4; t++){
          af[t] = *(const half8*)(Qb + (t*16 + l15)*72 + kc*32 + quad*8);
          bf[t] = *(const half8*)(Kb + (t*16 + l15)*72 + kc*32 + quad*8);
        }
        #pragma unroll
        for (int ti=0; ti<4; ti++)
          #pragma unroll
          for (int tj=0; tj<4; tj++)
            sacc[ti][tj] = mfma16(af[ti], bf[tj], sacc[ti][tj]);
      }
      #pragma unroll
      for (int ti=0; ti<4; ti++){
        #pragma unroll
        for (int i=0; i<4; i++){
          float mx = -1e30f;
          #pragma unroll
          for (int tj=0; tj<4; tj++){
            float sv = sacc[ti][tj][i]*0.125f + mbs[tj*16 + l15];
            sacc[ti][tj][i] = sv;
            mx = fmaxf(mx, sv);
          }
          #pragma unroll
          for (int off=1; off<16; off<<=1) mx = fmaxf(mx, __shfl_xor(mx, off, 64));
          float sum = 0.f;
          #pragma unroll
          for (int tj=0; tj<4; tj++){
            float pv = __expf(sacc[ti][tj][i] - mx);
            sacc[ti][tj][i] = pv; sum += pv;
          }
          #pragma unroll
          for (int off=1; off<16; off<<=1) sum += __shfl_xor(sum, off, 64);
          float inv = 1.f/sum;
          int q = ti*16 + quad*4 + i;
          #pragma unroll
          for (int tj=0; tj<4; tj++)
            Qb[q*72 + tj*16 + l15] = (f16)(sacc[ti][tj][i]*inv);
        }
      }
    }
    // ---- V = h0 @ wv_h^T ; transposed into Kb as V^T[d][token] ----
    {
      f32x4 va4[4][4] = {};
      #pragma unroll 4
      for (int ks=0; ks<16; ks++){
        half8 a[4], bv_[4];
        #pragma unroll
        for (int mt=0; mt<4; mt++)
          a[mt] = *(const half8*)(h0g + (rbase + mt*16 + l15)*512 + ks*32 + quad*8);
        #pragma unroll
        for (int nt=0; nt<4; nt++)
          bv_[nt] = *(const half8*)(Wq + (size_t)(1024 + h*64 + nt*16 + l15)*512 + ks*32 + quad*8);
        #pragma unroll
        for (int mt=0; mt<4; mt++)
          #pragma unroll
          for (int nt=0; nt<4; nt++)
            va4[mt][nt] = mfma16(a[mt], bv_[nt], va4[mt][nt]);
      }
      #pragma unroll
      for (int nt=0; nt<4; nt++){
        float vb = biasb[1024 + h*64 + nt*16 + l15];
        #pragma unroll
        for (int mt=0; mt<4; mt++)
          #pragma unroll
          for (int i=0; i<4; i++){
            int tok = mt*16 + quad*4 + i, d = nt*16 + l15;
            Kb[d*72 + tok] = (f16)(va4[mt][nt][i] + vb);
          }
      }
    }
    __syncthreads();
    // ---- PV: out[d][q]; write z into Z[q][h*64+d] ----
    {
      f32x4 zacc[4][4] = {};
      #pragma unroll
      for (int kc=0; kc<2; kc++){
        half8 vvf[4], ppf[4];
        #pragma unroll
        for (int t=0; t<4; t++){
          vvf[t] = *(const half8*)(Kb + (t*16 + l15)*72 + kc*32 + quad*8);
          ppf[t] = *(const half8*)(Qb + (t*16 + l15)*72 + kc*32 + quad*8);
        }
        #pragma unroll
        for (int ti=0; ti<4; ti++)
          #pragma unroll
          for (int tj=0; tj<4; tj++)
            zacc[ti][tj] = mfma16(vvf[ti], ppf[tj], zacc[ti][tj]);
      }
      #pragma unroll
      for (int ti=0; ti<4; ti++)
        #pragma unroll
        for (int tj=0; tj<4; tj++){
          int q = tj*16 + l15, d0 = ti*16 + quad*4;
          half4 pk;
          #pragma unroll
          for (int i=0; i<4; i++) pk[i] = (f16)zacc[ti][tj][i];
          *(half4*)(Z + q*520 + h*64 + d0) = pk;
        }
    }
    __syncthreads();
  }

  // generic 64x128-per-wave GEMM vs LDS A-plane [64][520] and global W [512][512]
  auto gemmNK = [&](const f16* Ap, const f16* Wg, f32x4 (&acc)[4][8]){
    #pragma unroll 2
    for (int ks=0; ks<16; ks++){
      half8 a[4], b[8];
      #pragma unroll
      for (int mt=0; mt<4; mt++)
        a[mt] = *(const half8*)(Ap + (mt*16 + l15)*520 + ks*32 + quad*8);
      #pragma unroll
      for (int nt=0; nt<8; nt++)
        b[nt] = *(const half8*)(Wg + (size_t)(wv*128 + nt*16 + l15)*512 + ks*32 + quad*8);
      #pragma unroll
      for (int mt=0; mt<4; mt++)
        #pragma unroll
        for (int nt=0; nt<8; nt++)
          acc[mt][nt] = mfma16(a[mt], b[nt], acc[mt][nt]);
    }
  };

  // ================= Phase B: WO + bo + h0 resid -> LN1 -> h_ln into Z ========
  {
    f32x4 oa[4][8] = {};
    gemmNK(Z, wbf + OFF_WO, oa);
    #pragma unroll
    for (int nt=0; nt<8; nt++){
      int c = wv*128 + nt*16 + l15;
      float bv = bo[c];
      #pragma unroll
      for (int mt=0; mt<4; mt++)
        #pragma unroll
        for (int i=0; i<4; i++){
          int r = mt*16 + quad*4 + i;
          oa[mt][nt][i] += bv + (float)h0g[(rbase + r)*512 + c];
        }
    }
    // LN1 stats (each wave covers all 64 rows x its 128 cols)
    #pragma unroll
    for (int mt=0; mt<4; mt++)
      #pragma unroll
      for (int i=0; i<4; i++){
        float s = 0.f, sq = 0.f;
        #pragma unroll
        for (int nt=0; nt<8; nt++){ float v = oa[mt][nt][i]; s += v; sq += v*v; }
        #pragma unroll
        for (int off=1; off<16; off<<=1){ s += __shfl_xor(s, off, 64); sq += __shfl_xor(sq, off, 64); }
        if (l15 == 0){
          int r = mt*16 + quad*4 + i;
          stS[r][wv] = s; stQ[r][wv] = sq;
        }
      }
    __syncthreads();
    float m_[4][4], rs_[4][4];
    #pragma unroll
    for (int mt=0; mt<4; mt++)
      #pragma unroll
      for (int i=0; i<4; i++){
        int r = mt*16 + quad*4 + i;
        float ts = stS[r][0] + stS[r][1] + stS[r][2] + stS[r][3];
        float tq = stQ[r][0] + stQ[r][1] + stQ[r][2] + stQ[r][3];
        float m = ts*(1.f/512.f);
        m_[mt][i] = m;
        rs_[mt][i] = rsqrtf(tq*(1.f/512.f) - m*m + 1e-5f);
      }
    #pragma unroll
    for (int nt=0; nt<8; nt++){
      int c = wv*128 + nt*16 + l15;
      float g1c = g1[c], be1c = be1[c];
      #pragma unroll
      for (int mt=0; mt<4; mt++)
        #pragma unroll
        for (int i=0; i<4; i++){
          int r = mt*16 + quad*4 + i;
          float hl = (oa[mt][nt][i] - m_[mt][i])*rs_[mt][i]*g1c + be1c;
          Z[r*520 + c] = (f16)hl;
        }
    }
  }
  __syncthreads();

  // ================= Phase C: FFN1 (relu) into SC plane ======================
  {
    f32x4 fa[4][8] = {};
    gemmNK(Z, wbf + OFF_W1, fa);
    #pragma unroll
    for (int nt=0; nt<8; nt++){
      int c = wv*128 + nt*16 + l15;
      float bv = b1f[c];
      #pragma unroll
      for (int mt=0; mt<4; mt++)
        #pragma unroll
        for (int i=0; i<4; i++){
          int r = mt*16 + quad*4 + i;
          SC[r*520 + c] = (f16)fmaxf(fa[mt][nt][i] + bv, 0.f);
        }
    }
  }
  __syncthreads();

  // ================= Phase D: FFN2 + resid -> LN2 -> masked pool -> out ======
  {
    f32x4 xa[4][8] = {};
    gemmNK(SC, wbf + OFF_W2, xa);
    #pragma unroll
    for (int nt=0; nt<8; nt++){
      int c = wv*128 + nt*16 + l15;
      float bv = b2f[c];
      #pragma unroll
      for (int mt=0; mt<4; mt++)
        #pragma unroll
        for (int i=0; i<4; i++){
          int r = mt*16 + quad*4 + i;
          xa[mt][nt][i] += bv + (float)Z[r*520 + c];
        }
    }
    // LN2 stats
    #pragma unroll
    for (int mt=0; mt<4; mt++)
      #pragma unroll
      for (int i=0; i<4; i++){
        float s = 0.f, sq = 0.f;
        #pragma unroll
        for (int nt=0; nt<8; nt++){ float v = xa[mt][nt][i]; s += v; sq += v*v; }
        #pragma unroll
        for (int off=1; off<16; off<<=1){ s += __shfl_xor(s, off, 64); sq += __shfl_xor(sq, off, 64); }
        if (l15 == 0){
          int r = mt*16 + quad*4 + i;
          stS[r][wv] = s; stQ[r][wv] = sq;
        }
      }
    __syncthreads();
    float m_[4][4], rs_[4][4], wA[4][4];
    #pragma unroll
    for (int mt=0; mt<4; mt++)
      #pragma unroll
      for (int i=0; i<4; i++){
        int r = mt*16 + quad*4 + i;
        float ts = stS[r][0] + stS[r][1] + stS[r][2] + stS[r][3];
        float tq = stQ[r][0] + stQ[r][1] + stQ[r][2] + stQ[r][3];
        float m = ts*(1.f/512.f);
        m_[mt][i] = m;
        rs_[mt][i] = rsqrtf(tq*(1.f/512.f) - m*m + 1e-5f);
        wA[mt][i] = vArr[r];
      }
    float cnt = 0.f;
    #pragma unroll
    for (int l=0; l<64; l++) cnt += vArr[l];
    float denom = fmaxf(cnt, 1.f);
    float pexv = cnt > 0.f ? 1.f : 0.f;
    int pidx = ng & 127;
    #pragma unroll
    for (int nt=0; nt<8; nt++){
      int c = wv*128 + nt*16 + l15;
      float p = 0.f;
      #pragma unroll
      for (int mt=0; mt<4; mt++)
        #pragma unroll
        for (int i=0; i<4; i++)
          p += wA[mt][i]*(xa[mt][nt][i] - m_[mt][i])*rs_[mt][i];
      p += __shfl_xor(p, 16, 64);
      p += __shfl_xor(p, 32, 64);
      if (quad == 0){
        float fr = __expf(-(float)(c & ~1) * (9.210340371976184f/512.f));
        float ang = (float)pidx * fr;
        float pe = (c & 1) ? cosf(ang) : sinf(ang);
        out[(size_t)ng*512 + c] = (g2[c]*p + be2[c]*cnt)/denom + eb[c]*(1.f - pexv) + pe;
      }
    }
  }
}

// ---------------- LayerNorm helper kernels removed (fused into patch_block) ---

__global__ __launch_bounds__(256) void cvt_f32_f16(const float* __restrict__ s, f16* __restrict__ d){
  int i = blockIdx.x*256 + threadIdx.x;
  d[i] = (f16)s[i];
}

// ---------------- graph attention on merged QKV (stride 1536), P=128 keys ----------------
__global__ __launch_bounds__(256) void attn_graph(
    f16* __restrict__ qkv, const float* __restrict__ pexists)
{
  __shared__ f16 Vt[64][136];
  __shared__ f16 Ps[4][32][136];
  __shared__ float pxs[128];
  const int tid = threadIdx.x, wv = tid>>6, lane = tid&63, l15 = lane&15, quad = lane>>4;
  const int b = blockIdx.x, h = blockIdx.y;
  if (tid < 128) pxs[tid] = pexists[b*128 + tid];
  const f16* Vb = qkv + 1024 + h*64;
  for (int i=0; i<32; i++){
    int e = tid + i*256, k = e>>6, d = e&63;
    Vt[d][k] = Vb[((size_t)b*128 + k)*1536 + d];
  }
  __syncthreads();
  const f16* Qb = qkv + h*64;
  const f16* Kb = qkv + 512 + h*64;
  const int qb = wv*32;
  f32x4 sacc[2][8] = {};
  #pragma unroll
  for (int kc=0; kc<2; kc++){
    half8 af[2], bf[8];
    #pragma unroll
    for (int ti=0; ti<2; ti++)
      af[ti] = *(const half8*)(Qb + ((size_t)b*128 + qb + ti*16 + l15)*1536 + kc*32 + quad*8);
    #pragma unroll
    for (int tj=0; tj<8; tj++)
      bf[tj] = *(const half8*)(Kb + ((size_t)b*128 + tj*16 + l15)*1536 + kc*32 + quad*8);
    #pragma unroll
    for (int ti=0; ti<2; ti++)
      #pragma unroll
      for (int tj=0; tj<8; tj++)
        sacc[ti][tj] = mfma16(af[ti], bf[tj], sacc[ti][tj]);
  }
  #pragma unroll
  for (int ti=0; ti<2; ti++){
    #pragma unroll
    for (int i=0; i<4; i++){
      int q = qb + ti*16 + quad*4 + i;
      float mx = -1e30f;
      #pragma unroll
      for (int tj=0; tj<8; tj++){
        int col = tj*16 + l15;
        int dd = q - col; if (dd < 0) dd = -dd;
        float tb = __logf(__expf(-(float)dd) + 1e-12f);
        float sv = sacc[ti][tj][i]*0.125f + tb + (pxs[col] > 0.f ? 0.f : -1e9f);
        sacc[ti][tj][i] = sv;
        mx = fmaxf(mx, sv);
      }
      #pragma unroll
      for (int off=1; off<16; off<<=1) mx = fmaxf(mx, __shfl_xor(mx, off, 64));
      float sum = 0.f;
      #pragma unroll
      for (int tj=0; tj<8; tj++){
        float pv = __expf(sacc[ti][tj][i] - mx);
        sacc[ti][tj][i] = pv; sum += pv;
      }
      #pragma unroll
      for (int off=1; off<16; off<<=1) sum += __shfl_xor(sum, off, 64);
      float inv = 1.f/sum;
      int ql = ti*16 + quad*4 + i;
      #pragma unroll
      for (int tj=0; tj<8; tj++)
        Ps[wv][ql][tj*16 + l15] = (f16)(sacc[ti][tj][i]*inv);
    }
  }
  __syncthreads();
  f32x4 zacc[4][2] = {};
  #pragma unroll
  for (int kc=0; kc<4; kc++){
    half8 va[4], pb[2];
    #pragma unroll
    for (int ti2=0; ti2<4; ti2++)
      va[ti2] = *(const half8*)(&Vt[ti2*16 + l15][kc*32 + quad*8]);
    #pragma unroll
    for (int tjq=0; tjq<2; tjq++)
      pb[tjq] = *(const half8*)(&Ps[wv][tjq*16 + l15][kc*32 + quad*8]);
    #pragma unroll
    for (int ti2=0; ti2<4; ti2++)
      #pragma unroll
      for (int tjq=0; tjq<2; tjq++)
        zacc[ti2][tjq] = mfma16(va[ti2], pb[tjq], zacc[ti2][tjq]);
  }
  __syncthreads();
  #pragma unroll
  for (int ti2=0; ti2<4; ti2++)
    #pragma unroll
    for (int tjq=0; tjq<2; tjq++){
      int ql = tjq*16 + l15, d0 = ti2*16 + quad*4;
      half4 pk;
      #pragma unroll
      for (int i=0; i<4; i++) pk[i] = (f16)zacc[ti2][tjq][i];
      *(half4*)(&Ps[wv][ql][d0]) = pk;
    }
  __syncthreads();
  {
    int q = tid>>1, hf = tid&1;
    const f16* src = &Ps[q>>5][q&31][hf*32];
    #pragma unroll
    for (int j=0; j<4; j++)
      *(uint4*)(qkv + ((size_t)b*128 + q)*1536 + h*64 + hf*32 + j*8) = *(const uint4*)(src + j*8);
  }
}

// ---------------- launcher ----------------
extern "C" void kernel_launch(void* const* d_in, const int* in_sizes, int n_in,
                              void* d_out, int out_size, void* d_ws, size_t ws_size,
                              hipStream_t stream)
{
  (void)in_sizes; (void)n_in; (void)out_size; (void)ws_size;
  const float* x    = (const float*)d_in[0];
  const float* tt   = (const float*)d_in[1];
  const int*   mask = (const int*)  d_in[2];
  const float* tsw  = (const float*)d_in[3];
  const float* tsb  = (const float*)d_in[4];
  const float* tpw  = (const float*)d_in[5];
  const float* tpb  = (const float*)d_in[6];
  const float* inpw = (const float*)d_in[7];
  const float* inpb = (const float*)d_in[8];
  const float* wq   = (const float*)d_in[9];
  const float* bq   = (const float*)d_in[10];
  const float* wk   = (const float*)d_in[11];
  const float* bk   = (const float*)d_in[12];
  const float* wv   = (const float*)d_in[13];
  const float* bv   = (const float*)d_in[14];
  const float* wo   = (const float*)d_in[15];
  const float* bo   = (const float*)d_in[16];
  const float* w1   = (const float*)d_in[17];
  const float* b1   = (const float*)d_in[18];
  const float* w2   = (const float*)d_in[19];
  const float* b2   = (const float*)d_in[20];
  const float* ln1g = (const float*)d_in[21];
  const float* ln1b = (const float*)d_in[22];
  const float* ln2g = (const float*)d_in[23];
  const float* ln2b = (const float*)d_in[24];
  const float* eb   = (const float*)d_in[25];
  const float* gwq  = (const float*)d_in[26];
  const float* gbq  = (const float*)d_in[27];
  const float* gwk  = (const float*)d_in[28];
  const float* gbk  = (const float*)d_in[29];
  const float* gwv  = (const float*)d_in[30];
  const float* gbv  = (const float*)d_in[31];
  const float* gwo  = (const float*)d_in[32];
  const float* gbo  = (const float*)d_in[33];
  float* out = (float*)d_out;

  char* wp = (char*)d_ws;
  auto alloc = [&](size_t bytes)->char*{
    char* p = wp; wp += (bytes + 255) & ~(size_t)255; return p;
  };
  f16*   wbf   = (f16*)  alloc((size_t)WBF_TOT*2);
  float* mb    = (float*)alloc((size_t)NTOK*64*4);
  float* pex   = (float*)alloc((size_t)NTOK*4);
  float* biasb = (float*)alloc((size_t)3*1536*4);
  f16*   ptsb  = (f16*)  alloc((size_t)CH*64*128*2);   // 33.5 MB
  f16*   bufA  = (f16*)  alloc((size_t)CH*64*512*2);   // h0 chunk, 134 MB
  f16*   hbf   = (f16*)  alloc((size_t)NTOK*512*2);    // stage-3 h f16
  f16*   qkvg  = (f16*)  alloc((size_t)NTOK*1536*2);   // stage-3 merged qkv

  conv_weights<<<dim3(1024,16),256,0,stream>>>(inpw,wq,wk,wv,wo,w1,w2,gwq,gwk,gwv,gwo,wbf,
                                               bq,bk,bv,gbq,gbk,gbv,biasb);
  build_mask<<<NTOK/4,256,0,stream>>>(mask, mb, pex);

  for (int ch=0; ch<NCHUNK; ch++){
    int nbase = ch*CH;
    int rowbase = nbase*64;
    pts_build<<<CH*64*128/256,256,0,stream>>>(x,tt,tsw,tsb,tpw,tpb,ptsb,rowbase);
    // h0 = pts @ inp_w^T + b (zero row0 of empty patches)
    gemm128<0,false,false,true ><<<dim3(CH*64/128,4),256,0,stream>>>(ptsb, wbf+OFF_INPW, inpb, bufA, nullptr, pex, 128, 128, 512, nbase);
    // fused tail: qkv+attn+wo+ln1+ffn+ln2+pool
    patch_block<<<CH,256,0,stream>>>(bufA, wbf, biasb, bo, b1, b2,
                                     ln1g, ln1b, ln2g, ln2b, eb, mb, mask, out, nbase);
  }

  for (int li=0; li<2; li++){
    cvt_f32_f16<<<NTOK*512/256,256,0,stream>>>(out, hbf);
    gemm128<0,false,false,false><<<dim3(32,12),256,0,stream>>>(hbf, wbf+OFF_GW + (size_t)li*4*512*512, biasb + 1536*(1+li), qkvg, nullptr, nullptr, 512, 512, 1536, 0);
    attn_graph<<<dim3(32,8),256,0,stream>>>(qkvg, pex);
    // h += (z @ gwo^T + gbo) * pexists (in place on f32 d_out)
    gemm128<2,false,true ,false><<<dim3(32,4),256,0,stream>>>(qkvg, wbf+OFF_GW + (size_t)(li*4+3)*512*512, gbo+li*512, out, out, pex, 512, 1536, 512, 0);
  }
}